// Round 3
// baseline (307.311 us; speedup 1.0000x reference)
//
#include <hip/hip_runtime.h>

// Broadcast helpers via v_readlane (uniform SGPR result).
__device__ __forceinline__ int rdlane_i(int v, int l) {
    return __builtin_amdgcn_readlane(v, l);
}
__device__ __forceinline__ float rdlane_f(float v, int l) {
    return __int_as_float(__builtin_amdgcn_readlane(__float_as_int(v), l));
}

// One butterfly step of a 64-lane INTEGER max (order-equivalent to float
// max for our keys: alive keys are non-negative floats, dead keys are
// -inf-packed => hugely negative ints; bound_ctrl injects 0 which never
// beats a real alive key).
template <int CTRL>
__device__ __forceinline__ int dpp_imax_step(int x) {
    int t = __builtin_amdgcn_update_dpp(0, x, CTRL, 0xF, 0xF, true);
    return (t > x) ? t : x;
}

// Full 64-lane int max; result valid in lane 63.
__device__ __forceinline__ int wave_imax_to_lane63(int x) {
    x = dpp_imax_step<0xB1>(x);   // xor 1
    x = dpp_imax_step<0x4E>(x);   // xor 2
    x = dpp_imax_step<0x141>(x);  // row_half_mirror (xor within 8)
    x = dpp_imax_step<0x140>(x);  // row_mirror      (xor within 16)
    x = dpp_imax_step<0x142>(x);  // row_bcast15     (16 -> 32)
    x = dpp_imax_step<0x143>(x);  // row_bcast31     (32 -> 64)
    return x;
}

// TWO waves per 64x64 matrix, columns interleaved by parity:
//   lane i owns row i (both waves), wave-parity w owns columns j (j&1==w),
//   stored as A[t] = column 2t+w. 32 floats/lane + ~18 working regs fits
//   the 64-reg/8-wave arch-VGPR budget => the allocator has no reason to
//   home A in AGPRs (R1/R2 rocprof: A[64] went to AGPRs at ANY budget and
//   every access paid v_accvgpr_read/write — ~3x VALU inflation, 16K vs
//   5.6K instr/wave; occupancy changes 5.1->3.2 waves/SIMD had ZERO
//   duration effect, proving issue-bound).
//
// Per pivot step k: the wave owning column k (w == k&1) does the argmax,
// computes inv/logdet and the per-row multiplier m, publishes {m, p} via
// LDS (double-buffered by k parity: the k+2 overwrite is ordered after
// the k+1 barrier, so ONE __syncthreads per step suffices); both waves
// then rank-1-update their own columns with within-wave readlanes.
//
// Block = 256 threads = 4 waves: {0,1} -> spin-up matrix, {2,3} -> spin-dn.
__global__ __launch_bounds__(256, 4) void slater_logdet_kernel(
        const float* __restrict__ rs, const float* __restrict__ log_alpha_p,
        float* __restrict__ out) {
    const int b    = blockIdx.x;
    const int tid  = threadIdx.x;
    const int wv   = tid >> 6;       // 0..3
    const int spin = wv >> 1;        // 0 = up, 1 = dn
    const int w    = wv & 1;         // column parity this wave owns
    const int lane = tid & 63;

    const float Lbox = 10.0f;
    const float PI_F = 3.14159265358979323846f;

    float alpha = __expf(log_alpha_p[0]);
    alpha = fminf(fmaxf(alpha, 0.5f / (Lbox * Lbox)), 200.0f / (Lbox * Lbox));

    // Electron position for this lane (row index = electron index).
    const float* rp = rs + (size_t)b * 384 + (size_t)(spin * 64 + lane) * 3;
    float x = rp[0], y = rp[1], z = rp[2];

    float sx, cx, sy, cy, sz, cz;
    __sincosf(x * (PI_F / Lbox), &sx, &cx);
    __sincosf(y * (PI_F / Lbox), &sy, &cy);
    __sincosf(z * (PI_F / Lbox), &sz, &cz);

    // Separable build: Phi[i][j] = ex[mx]*ey[my]*ez[mz], j = mx*16+my*4+mz.
    const float off = spin ? 0.5f : 0.0f;
    const float LPI = Lbox / PI_F;
    float ex[4], ey[4], ez[4];
#pragma unroll
    for (int m = 0; m < 4; ++m) {
        float sp, cp;
        __sincosf((PI_F * 0.25f) * ((float)m + off), &sp, &cp);
        float dx = LPI * (sx * cp - cx * sp);
        float dy = LPI * (sy * cp - cy * sp);
        float dz = LPI * (sz * cp - cz * sp);
        ex[m] = __expf(-alpha * dx * dx);
        ey[m] = __expf(-alpha * dy * dy);
        ez[m] = __expf(-alpha * dz * dz);
    }

    // Build this wave's 32 columns. Branch on (uniform) parity so every
    // ex/ey/ez index is a compile-time constant (no scratch).
    float A[32];
    if (w == 0) {
#pragma unroll
        for (int t = 0; t < 32; ++t) {
            const int j = 2 * t;
            A[t] = ex[j >> 4] * ey[(j >> 2) & 3] * ez[j & 3];
        }
    } else {
#pragma unroll
        for (int t = 0; t < 32; ++t) {
            const int j = 2 * t + 1;
            A[t] = ex[j >> 4] * ey[(j >> 2) & 3] * ez[j & 3];
        }
    }

    // {m, p} exchange buffers, double-buffered by pivot parity.
    __shared__ float mbuf[2][2][64];   // [spin][k&1][lane]
    __shared__ int   pbuf[2][2];       // [spin][k&1]
    __shared__ float partial[4];

    // LU with partial pivoting, row-owner layout, NO physical row swap:
    // flag = -inf marks rows already used as pivots (excluded from argmax).
    // Pivot search packs the lane index into the low 6 mantissa bits and
    // takes an integer max — winner's lane falls out of the max value.
    float flag   = 0.0f;
    float logdet = 0.0f;
#pragma unroll
    for (int k = 0; k < 64; ++k) {
        const int par = k & 1;
        int   ps = 0;
        float m  = 0.0f;
        if (w == par) {                       // this wave owns column k
            const int tk = k >> 1;
            float key = fabsf(A[tk]) + flag;
            int   ki  = (__float_as_int(key) & ~63) | lane;
            int   g   = rdlane_i(wave_imax_to_lane63(ki), 63);
            ps = g & 63;                      // pivot row's physical lane
            float pv  = rdlane_f(A[tk], ps);
            float inv = __builtin_amdgcn_rcpf(pv);
            inv = inv * (2.0f - pv * inv);    // 1 Newton step
            logdet += __logf(fabsf(pv));
            m = A[tk] * inv;                  // per-row multiplier
            mbuf[spin][par][lane] = m;
            if (lane == 0) pbuf[spin][par] = ps;
        }
        __syncthreads();
        if (w != par) {                       // partner: fetch {m, p}
            m  = mbuf[spin][par][lane];
            ps = __builtin_amdgcn_readfirstlane(pbuf[spin][par]);
        }

        // Mark pivot row dead for future argmaxes (both waves track this).
        flag = (lane == ps) ? -__builtin_huge_valf() : flag;

        // Rank-1 update of this wave's columns. Start at t = k>>1: covers
        // all columns > k plus <=2 already-eliminated ones (never read
        // again — harmless; keeps ONE shared loop instead of per-parity
        // duplicates). Constant bounds after unroll => pure VGPR indexing.
#pragma unroll
        for (int t = (k >> 1); t < 32; ++t) {
            float s = rdlane_f(A[t], ps);     // pivot-row elem -> SGPR
            A[t] = __builtin_fmaf(-m, s, A[t]);
        }
    }

    // Each wave accumulated logdet only over the pivot steps it owned.
    if (lane == 0) partial[wv] = logdet;
    __syncthreads();
    if (tid == 0) out[b] = partial[0] + partial[1] + partial[2] + partial[3];
}

extern "C" void kernel_launch(void* const* d_in, const int* in_sizes, int n_in,
                              void* d_out, int out_size, void* d_ws, size_t ws_size,
                              hipStream_t stream) {
    const float* rs = (const float*)d_in[0];
    const float* la = (const float*)d_in[1];
    float* out      = (float*)d_out;
    slater_logdet_kernel<<<out_size, 256, 0, stream>>>(rs, la, out);
}

// Round 4
// 288.542 us; speedup vs baseline: 1.0651x; 1.0651x over previous
//
#include <hip/hip_runtime.h>

// Broadcast helpers via v_readlane (uniform SGPR result).
__device__ __forceinline__ int rdlane_i(int v, int l) {
    return __builtin_amdgcn_readlane(v, l);
}
__device__ __forceinline__ float rdlane_f(float v, int l) {
    return __int_as_float(__builtin_amdgcn_readlane(__float_as_int(v), l));
}

// One butterfly step of a 64-lane INTEGER max (order-equivalent to float
// max for our keys: alive keys are non-negative floats, dead keys are
// -inf-packed => hugely negative ints; bound_ctrl injects 0 which never
// beats a real alive key).
template <int CTRL>
__device__ __forceinline__ int dpp_imax_step(int x) {
    int t = __builtin_amdgcn_update_dpp(0, x, CTRL, 0xF, 0xF, true);
    return (t > x) ? t : x;
}

// Full 64-lane int max; result valid in lane 63.
__device__ __forceinline__ int wave_imax_to_lane63(int x) {
    x = dpp_imax_step<0xB1>(x);   // xor 1
    x = dpp_imax_step<0x4E>(x);   // xor 2
    x = dpp_imax_step<0x141>(x);  // row_half_mirror (xor within 8)
    x = dpp_imax_step<0x140>(x);  // row_mirror      (xor within 16)
    x = dpp_imax_step<0x142>(x);  // row_bcast15     (16 -> 32)
    x = dpp_imax_step<0x143>(x);  // row_bcast31     (32 -> 64)
    return x;
}

// One wave = one 64x64 matrix, lane i owns ROW i in registers A[0..63].
// Block = 128 threads: wave 0 -> spin-up matrix, wave 1 -> spin-dn matrix.
//
// WHY INLINE ASM IN THE INNER LOOP (rocprof history):
//   R0/R1: VGPR_Count=36, dur 243us.  R2 (+waves_per_eu(4,4)): VGPR=52,
//   dur 243us.  R3 (2-wave split, A[32]): VGPR=24, dur 266us.  In every
//   variant the allocator homed the fully-unrolled A[] array in AGPRs
//   (VGPR_Count < array size each time) and wrapped every access in
//   v_accvgpr_read/write — measured ~16-19K VALU instr per matrix vs the
//   ~6K floor, i.e. ~3x inflation, with VALUBusy >90% (pure issue-bound:
//   occupancy 40%->83% changed duration by 0).  No attribute stops that
//   heuristic.  The "+v" asm constraint below does: it makes AGPR homing
//   cost explicit moves per touch, so A[] stays in arch VGPRs and the
//   inner update is exactly 2 VALU ops (v_readlane + v_fmac) per element.
__global__ __launch_bounds__(128)
__attribute__((amdgpu_waves_per_eu(2, 4)))   // arch-VGPR budget 256: room for A[64]+~25 working regs
void slater_logdet_kernel(
        const float* __restrict__ rs, const float* __restrict__ log_alpha_p,
        float* __restrict__ out) {
    const int b    = blockIdx.x;
    const int tid  = threadIdx.x;
    const int wave = tid >> 6;   // 0 = up, 1 = dn
    const int lane = tid & 63;

    const float Lbox = 10.0f;
    const float PI_F = 3.14159265358979323846f;

    float alpha = __expf(log_alpha_p[0]);
    alpha = fminf(fmaxf(alpha, 0.5f / (Lbox * Lbox)), 200.0f / (Lbox * Lbox));

    // Electron position for this lane (row index = electron index).
    const float* rp = rs + (size_t)b * 384 + (size_t)(wave * 64 + lane) * 3;
    float x = rp[0], y = rp[1], z = rp[2];

    float sx, cx, sy, cy, sz, cz;
    __sincosf(x * (PI_F / Lbox), &sx, &cx);
    __sincosf(y * (PI_F / Lbox), &sy, &cy);
    __sincosf(z * (PI_F / Lbox), &sz, &cz);

    // Separable build: Phi[i][j] = ex[mx]*ey[my]*ez[mz], j = mx*16+my*4+mz.
    // Only 12 exps + ~80 muls per lane (vs 64 exps in the column layout).
    const float off = wave ? 0.5f : 0.0f;
    const float LPI = Lbox / PI_F;
    float ex[4], ey[4], ez[4];
#pragma unroll
    for (int m = 0; m < 4; ++m) {
        float sp, cp;
        __sincosf((PI_F * 0.25f) * ((float)m + off), &sp, &cp);
        float dx = LPI * (sx * cp - cx * sp);
        float dy = LPI * (sy * cp - cy * sp);
        float dz = LPI * (sz * cp - cz * sp);
        ex[m] = __expf(-alpha * dx * dx);
        ey[m] = __expf(-alpha * dy * dy);
        ez[m] = __expf(-alpha * dz * dz);
    }
    float exy[16];
#pragma unroll
    for (int q = 0; q < 16; ++q) exy[q] = ex[q >> 2] * ey[q & 3];
    float A[64];
#pragma unroll
    for (int j = 0; j < 64; ++j) A[j] = exy[j >> 2] * ez[j & 3];

    // LU with partial pivoting, row-owner layout, NO physical row swap:
    // pivot rows stay in their lane; flag = -inf marks them dead so the
    // argmax never selects them again. det sign is irrelevant (log|det|).
    //
    // Pivot search: pack the lane index into the low 6 bits of the key's
    // mantissa and take an integer max — the winning lane index falls out
    // of the max result itself (no ballot/ffs).
    float flag   = 0.0f;   // 0 while alive, -inf once used as pivot row
    float logdet = 0.0f;
#pragma unroll
    for (int k = 0; k < 64; ++k) {
        // key = |A[k]| for alive rows, -inf for dead rows (one v_add w/ |mod|)
        float key = fabsf(A[k]) + flag;
        int   ki  = (__float_as_int(key) & ~63) | lane;  // keep sign bit!
        int   g   = rdlane_i(wave_imax_to_lane63(ki), 63);
        int   p   = g & 63;                        // pivot row's physical lane

        float pv  = rdlane_f(A[k], p);
        float inv = __builtin_amdgcn_rcpf(pv);
        inv = inv * (2.0f - pv * inv);             // 1 Newton step (~0.5 ulp)
        logdet += __logf(fabsf(pv));

        // Mark pivot row dead for future argmaxes.
        flag = (lane == p) ? -__builtin_huge_valf() : flag;

        // One multiplier per lane; lane p gets m~=1 and self-annihilates
        // (its row is never read again), dead lanes have A[k]=~0.
        float m  = A[k] * inv;
        float nm = -m;

        // Rank-1 update, 2 VALU ops per element BY CONSTRUCTION:
        //   v_readlane_b32 sS, vA[j], sP   (pivot-row elem -> SGPR)
        //   v_fmac_f32     vA[j], sS, vNM  (A[j] += (-m) * s; src0=SGPR ok)
        // "+v" pins A[j] to an arch VGPR at every use, defeating the
        // AGPR-homing heuristic. Independent chains across j => full ILP.
#pragma unroll
        for (int j = k + 1; j < 64; ++j) {
            float s_tmp;
            asm("v_readlane_b32 %1, %0, %3\n\t"
                "v_fmac_f32 %0, %1, %2"
                : "+v"(A[j]), "=&s"(s_tmp)
                : "v"(nm), "s"(p));
        }
    }

    // logdet is lane-uniform. Combine the two spins.
    __shared__ float partial[2];
    if (lane == 0) partial[wave] = logdet;
    __syncthreads();
    if (tid == 0) out[b] = partial[0] + partial[1];
}

extern "C" void kernel_launch(void* const* d_in, const int* in_sizes, int n_in,
                              void* d_out, int out_size, void* d_ws, size_t ws_size,
                              hipStream_t stream) {
    const float* rs = (const float*)d_in[0];
    const float* la = (const float*)d_in[1];
    float* out      = (float*)d_out;
    slater_logdet_kernel<<<out_size, 128, 0, stream>>>(rs, la, out);
}